// Round 2
// baseline (228.770 us; speedup 1.0000x reference)
//
#include <hip/hip_runtime.h>
#include <math.h>

// LayerNorm(Re(FFT(x, axis=-1))), x: (B=4, N=4096, C=2048) fp32.
// One 256-thread block per PAIR of rows: z = x_even + i*x_odd.
// Ping-pong Stockham FFT (self-sorting, NO in-place updates, no bit-reversal):
// 5 radix-4 stages + 1 radix-2 stage, twiddles on the fly via __sincosf.

#define TPB 256
#define CD  2048

// One Stockham radix-4 stage: sub-transform size N_, stride S_ (S_*N_ == 2048).
// Butterfly b in [0,512): q = b & (S_-1), p = b >> log2(S_).
// Reads  src[b + 512k] (lane-stride-1, conflict-free).
// Writes dst[q + 4*S_*p + r*S_] = W_N^(p*r) * t_r.
template<int N_, int S_>
__device__ __forceinline__ void r4_stage(const float2* __restrict__ src,
                                         float2* __restrict__ dst, int t)
{
    const float theta0 = -6.28318530717958647692f / (float)N_;
#pragma unroll
    for (int it = 0; it < 2; ++it) {
        const int b = t + TPB * it;            // [0, 512)
        const int q = b & (S_ - 1);
        const int p = b / S_;                  // compile-time shift
        float2 x0 = src[b];
        float2 x1 = src[b + 512];
        float2 x2 = src[b + 1024];
        float2 x3 = src[b + 1536];
        float apc_r = x0.x + x2.x, apc_i = x0.y + x2.y;
        float amc_r = x0.x - x2.x, amc_i = x0.y - x2.y;
        float bpd_r = x1.x + x3.x, bpd_i = x1.y + x3.y;
        float bmd_r = x1.x - x3.x, bmd_i = x1.y - x3.y;
        // t0 = apc+bpd; t2 = apc-bpd; t1 = amc - i*bmd; t3 = amc + i*bmd
        float t0r = apc_r + bpd_r, t0i = apc_i + bpd_i;
        float t2r = apc_r - bpd_r, t2i = apc_i - bpd_i;
        float t1r = amc_r + bmd_i, t1i = amc_i - bmd_r;
        float t3r = amc_r - bmd_i, t3i = amc_i + bmd_r;
        float s1, c1;
        __sincosf(theta0 * (float)p, &s1, &c1);
        const float c2 = c1 * c1 - s1 * s1, s2 = 2.0f * c1 * s1;
        const float c3 = c1 * c2 - s1 * s2, s3 = c1 * s2 + s1 * c2;
        const int o = q + 4 * S_ * p;
        dst[o]          = make_float2(t0r, t0i);
        dst[o + S_]     = make_float2(c1 * t1r - s1 * t1i, c1 * t1i + s1 * t1r);
        dst[o + 2 * S_] = make_float2(c2 * t2r - s2 * t2i, c2 * t2i + s2 * t2r);
        dst[o + 3 * S_] = make_float2(c3 * t3r - s3 * t3i, c3 * t3i + s3 * t3r);
    }
}

__global__ __launch_bounds__(TPB) void fourier_ln_kernel(
    const float* __restrict__ x,
    const float* __restrict__ gamma,
    const float* __restrict__ beta,
    float* __restrict__ out)
{
    __shared__ float2 bufA[CD];
    __shared__ float2 bufB[CD];   // reused as reduction scratch after last read

    const int t = threadIdx.x;
    const long long row0 = 2LL * (long long)blockIdx.x;
    const long long row1 = row0 + 1;

    // Load: row0 -> real, row1 -> imag (float4 global loads, float2 LDS writes)
    const float4* x0 = (const float4*)(x + row0 * CD);
    const float4* x1 = (const float4*)(x + row1 * CD);
#pragma unroll
    for (int i = 0; i < 2; i++) {
        int idx = t + TPB * i;                 // 512 float4 per row
        float4 a = x0[idx];
        float4 b = x1[idx];
        int base = 4 * idx;
        bufA[base + 0] = make_float2(a.x, b.x);
        bufA[base + 1] = make_float2(a.y, b.y);
        bufA[base + 2] = make_float2(a.z, b.z);
        bufA[base + 3] = make_float2(a.w, b.w);
    }
    __syncthreads();

    r4_stage<2048, 1>(bufA, bufB, t);  __syncthreads();
    r4_stage< 512, 4>(bufB, bufA, t);  __syncthreads();
    r4_stage< 128, 16>(bufA, bufB, t); __syncthreads();
    r4_stage<  32, 64>(bufB, bufA, t); __syncthreads();
    r4_stage<   8, 256>(bufA, bufB, t); __syncthreads();

    // Final radix-2 stage: n=2, s=1024, p=0 (twiddle = 1). bufB -> bufA.
#pragma unroll
    for (int it = 0; it < 4; ++it) {
        int b = t + TPB * it;                  // [0, 1024)
        float2 u = bufB[b];
        float2 v = bufB[b + 1024];
        bufA[b]        = make_float2(u.x + v.x, u.y + v.y);
        bufA[b + 1024] = make_float2(u.x - v.x, u.y - v.y);
    }
    __syncthreads();
    // bufA now holds Z[k] = FFT(row0 + i*row1) in NATURAL order. bufB is dead.

    // Untangle + LayerNorm moments. Re X0[k] = (ReZ[k]+ReZ[N-k])/2,
    // Re X1[k] = (ImZ[k]+ImZ[N-k])/2. Both gathers are lane-stride-1.
    float y0v[8], y1v[8];
    float s0 = 0.f, ss0 = 0.f, s1 = 0.f, ss1 = 0.f;
#pragma unroll
    for (int i = 0; i < 8; i++) {
        int k = t + TPB * i;
        int rv = (CD - k) & (CD - 1);
        float2 zk = bufA[k];
        float2 zr = bufA[rv];
        float a = 0.5f * (zk.x + zr.x);
        float b = 0.5f * (zk.y + zr.y);
        y0v[i] = a; y1v[i] = b;
        s0 += a; ss0 += a * a;
        s1 += b; ss1 += b * b;
    }

    // Wave-64 shuffle reduce, then cross-wave via LDS (overlaid on bufB).
#pragma unroll
    for (int off = 32; off > 0; off >>= 1) {
        s0  += __shfl_down(s0,  off, 64);
        ss0 += __shfl_down(ss0, off, 64);
        s1  += __shfl_down(s1,  off, 64);
        ss1 += __shfl_down(ss1, off, 64);
    }
    float* rmem = (float*)bufB;                // [0..15] partials, [16..19] bcast
    const int wave = t >> 6;
    if ((t & 63) == 0) {
        rmem[4 * wave + 0] = s0;
        rmem[4 * wave + 1] = ss0;
        rmem[4 * wave + 2] = s1;
        rmem[4 * wave + 3] = ss1;
    }
    __syncthreads();
    if (t == 0) {
        float S0 = 0.f, SS0 = 0.f, S1 = 0.f, SS1 = 0.f;
#pragma unroll
        for (int w = 0; w < 4; w++) {
            S0  += rmem[4 * w + 0];
            SS0 += rmem[4 * w + 1];
            S1  += rmem[4 * w + 2];
            SS1 += rmem[4 * w + 3];
        }
        const float inv = 1.0f / (float)CD;
        float mu0 = S0 * inv, mu1 = S1 * inv;
        float v0 = SS0 * inv - mu0 * mu0;
        float v1 = SS1 * inv - mu1 * mu1;
        rmem[16] = mu0; rmem[17] = rsqrtf(v0 + 1e-5f);
        rmem[18] = mu1; rmem[19] = rsqrtf(v1 + 1e-5f);
    }
    __syncthreads();
    const float mu0 = rmem[16], r0 = rmem[17];
    const float mu1 = rmem[18], r1 = rmem[19];

    float* o0 = out + row0 * CD;
    float* o1 = out + row1 * CD;
#pragma unroll
    for (int i = 0; i < 8; i++) {
        int k = t + TPB * i;
        float g = gamma[k], be = beta[k];
        o0[k] = (y0v[i] - mu0) * r0 * g + be;
        o1[k] = (y1v[i] - mu1) * r1 * g + be;
    }
}

extern "C" void kernel_launch(void* const* d_in, const int* in_sizes, int n_in,
                              void* d_out, int out_size, void* d_ws, size_t ws_size,
                              hipStream_t stream) {
    (void)in_sizes; (void)n_in; (void)d_ws; (void)ws_size; (void)out_size;
    const float* x     = (const float*)d_in[0];
    const float* gamma = (const float*)d_in[1];
    const float* beta  = (const float*)d_in[2];
    float* out = (float*)d_out;

    const int total_rows = 4 * 4096;           // B * N
    const int blocks = total_rows / 2;         // one block per row pair
    fourier_ln_kernel<<<blocks, TPB, 0, stream>>>(x, gamma, beta, out);
}